// Round 12
// baseline (558.601 us; speedup 1.0000x reference)
//
#include <hip/hip_runtime.h>
#include <cstdint>
#include <cstddef>

// GraphCluster: 3-layer GCN + assign head, 100K nodes / 1.6M edges.
// R1: hierarchical scan. R2: f16-MFMA GEMMs. R3: f16 intermediates.
// R4 bucketed fill REVERTED (hot-cursor atomics). R6 agg unroll-8 REVERTED.
// R7: scan-based counting-sort CSR build. R9/R10: 16-row GEMM tiles +
// lane-ordered W frags. R11: agg packed-f16 + contiguous runs (fetch-bound at
// 3.37TB/s, near random-gather ceiling). R12: GEMM v3 — per-wave B-frag hoist
// (loop-invariant, loaded once) + NITER=4 row-tiles with A-prefetch pipeline
// (was: 16 loads + vmcnt(0) + 8 MFMA per wave, 4x redundant B traffic).

#define SCAN_CHUNK 2048

typedef _Float16 half8 __attribute__((ext_vector_type(8)));
typedef float floatx4 __attribute__((ext_vector_type(4)));

// ---------------------------------------------------------------- generic scan
__global__ __launch_bounds__(256) void scan_partial_k(const int* __restrict__ cnt, int N,
                                                      int* __restrict__ bsum) {
  __shared__ int red[256];
  int b = blockIdx.x, t = threadIdx.x;
  int base = b * SCAN_CHUNK + t * 8;
  int s = 0;
#pragma unroll
  for (int i = 0; i < 8; ++i) {
    int idx = base + i;
    if (idx < N) s += cnt[idx];
  }
  red[t] = s;
  __syncthreads();
  for (int off = 128; off > 0; off >>= 1) {
    if (t < off) red[t] += red[t + off];
    __syncthreads();
  }
  if (t == 0) bsum[b] = red[0];
}

__global__ __launch_bounds__(64) void scan_bsum_k(int* __restrict__ bsum, int NB) {
  int lane = threadIdx.x;
  int per = (NB + 63) >> 6;
  int beg = lane * per;
  int end = min(beg + per, NB);
  int s = 0;
  for (int i = beg; i < end; ++i) s += bsum[i];
  int ps = s;
  for (int off = 1; off < 64; off <<= 1) {
    int u = __shfl_up(ps, off, 64);
    if (lane >= off) ps += u;
  }
  int run = ps - s;
  for (int i = beg; i < end; ++i) {
    int c = bsum[i];
    bsum[i] = run;
    run += c;
  }
}

__global__ __launch_bounds__(256) void scan_apply_k(const int* __restrict__ cnt,
                                                    const int* __restrict__ bsum_excl, int N,
                                                    int* __restrict__ rowptr,
                                                    int* __restrict__ cursor, int E) {
  __shared__ int wave_sums[4];
  int b = blockIdx.x, t = threadIdx.x;
  int base = b * SCAN_CHUNK + t * 8;
  int v[8];
  int s = 0;
#pragma unroll
  for (int i = 0; i < 8; ++i) {
    int idx = base + i;
    v[i] = (idx < N) ? cnt[idx] : 0;
    s += v[i];
  }
  int lane = t & 63, wave = t >> 6;
  int ps = s;
  for (int off = 1; off < 64; off <<= 1) {
    int u = __shfl_up(ps, off, 64);
    if (lane >= off) ps += u;
  }
  if (lane == 63) wave_sums[wave] = ps;
  __syncthreads();
  int woff = 0;
  for (int w = 0; w < 4; ++w)
    if (w < wave) woff += wave_sums[w];
  int excl = woff + (ps - s) + bsum_excl[b];
#pragma unroll
  for (int i = 0; i < 8; ++i) {
    int idx = base + i;
    if (idx < N) {
      rowptr[idx] = excl;
      cursor[idx] = excl;
      excl += v[i];
    }
  }
  if (b == 0 && t == 0) rowptr[N] = E;
}

// ------------------------------------------------- scan-sorted CSR build
__global__ __launch_bounds__(256) void p1a_hist_k(const int* __restrict__ dst, int E, int G,
                                                  int B, int chunk, int* __restrict__ M) {
  __shared__ int h[256];
  int g = blockIdx.x, t = threadIdx.x;
  for (int i = t; i < B; i += 256) h[i] = 0;
  __syncthreads();
  int ebeg = g * chunk, eend = min(ebeg + chunk, E);
  for (int e = ebeg + t; e < eend; e += 256) atomicAdd(&h[dst[e] >> 9], 1);
  __syncthreads();
  for (int b = t; b < B; b += 256) M[(size_t)b * G + g] = h[b];
}

__global__ __launch_bounds__(256) void p1c_scatter_k(const int* __restrict__ src,
                                                     const int* __restrict__ dst, int E, int G,
                                                     int B, int chunk,
                                                     const int* __restrict__ scanned,
                                                     uint32_t* __restrict__ tmp) {
  __shared__ int off[256];
  int g = blockIdx.x, t = threadIdx.x;
  for (int b = t; b < B; b += 256) off[b] = scanned[(size_t)b * G + g];
  __syncthreads();
  int ebeg = g * chunk, eend = min(ebeg + chunk, E);
  for (int e = ebeg + t; e < eend; e += 256) {
    int d = dst[e];
    int b = d >> 9;
    int pos = atomicAdd(&off[b], 1);  // LDS cursor, private to this block
    tmp[pos] = ((uint32_t)(d & 511) << 17) | (uint32_t)src[e];
  }
}

__global__ __launch_bounds__(256) void p2_build_k(const uint32_t* __restrict__ tmp,
                                                  const int* __restrict__ scanned, int G, int N,
                                                  int E, int* __restrict__ rowptr,
                                                  int* __restrict__ col,
                                                  float* __restrict__ dinv) {
  __shared__ int hist[512];
  __shared__ int cur[512];
  __shared__ int wsum[4];
  int b = blockIdx.x, t = threadIdx.x;
  int node0 = b << 9;
  int nn = min(512, N - node0);
  int sbeg = scanned[(size_t)b * G];
  int send = scanned[(size_t)(b + 1) * G];
  for (int i = t; i < 512; i += 256) hist[i] = 0;
  __syncthreads();
  for (int e = sbeg + t; e < send; e += 256) atomicAdd(&hist[tmp[e] >> 17], 1);
  __syncthreads();
  int h0 = hist[2 * t], h1 = hist[2 * t + 1];
  int s = h0 + h1;
  int lane = t & 63, w = t >> 6;
  int ps = s;
  for (int o = 1; o < 64; o <<= 1) {
    int u = __shfl_up(ps, o, 64);
    if (lane >= o) ps += u;
  }
  if (lane == 63) wsum[w] = ps;
  __syncthreads();
  int woff = 0;
  for (int k = 0; k < 4; ++k)
    if (k < w) woff += wsum[k];
  int excl = sbeg + woff + (ps - s);
  if (2 * t < nn) {
    rowptr[node0 + 2 * t] = excl;
    cur[2 * t] = excl;
    dinv[node0 + 2 * t] = rsqrtf((float)(h0 + 1));
  }
  if (2 * t + 1 < nn) {
    rowptr[node0 + 2 * t + 1] = excl + h0;
    cur[2 * t + 1] = excl + h0;
    dinv[node0 + 2 * t + 1] = rsqrtf((float)(h1 + 1));
  }
  if (b == 0 && t == 0) rowptr[N] = E;
  __syncthreads();
  for (int e = sbeg + t; e < send; e += 256) {
    uint32_t u = tmp[e];
    int pos = atomicAdd(&cur[u >> 17], 1);
    col[pos] = (int)(u & 0x1FFFF);
  }
}

// ------------------------------------------------- fallback CSR build (N large)
__global__ __launch_bounds__(256) void count_edges_k(const int* __restrict__ dst, int E,
                                                     int* __restrict__ cnt) {
  int idx = blockIdx.x * blockDim.x + threadIdx.x;
  int stride = gridDim.x * blockDim.x;
  for (int e = idx; e < E; e += stride) atomicAdd(&cnt[dst[e]], 1);
}

__global__ __launch_bounds__(256) void dinv_k(const int* __restrict__ cnt,
                                              float* __restrict__ dinv, int N) {
  int i = blockIdx.x * blockDim.x + threadIdx.x;
  if (i < N) dinv[i] = rsqrtf((float)(cnt[i] + 1));
}

__global__ __launch_bounds__(256) void fill_k(const int* __restrict__ src,
                                              const int* __restrict__ dst, int E,
                                              int* __restrict__ cursor, int* __restrict__ col) {
  int idx = blockIdx.x * blockDim.x + threadIdx.x;
  int stride = gridDim.x * blockDim.x;
  for (int e = idx; e < E; e += stride) {
    int d = dst[e];
    int pos = atomicAdd(&cursor[d], 1);
    col[pos] = src[e];
  }
}

// ---------------------------------------------------------------- weight prep
// Lane-ordered MFMA B-fragments (see R9 comment for layout).
__global__ __launch_bounds__(256) void wprep_k(const float* __restrict__ fc1_W,
                                               const float* __restrict__ fc2_W,
                                               const float* __restrict__ gcn_W,
                                               const float* __restrict__ assign_W,
                                               _Float16* __restrict__ Wb) {
  int idx = blockIdx.x * 256 + threadIdx.x;
  if (idx < 5 * 16384) {
    int mat = idx >> 14;
    int r = idx & 16383;
    int t = r >> 11;
    int ktb = (r >> 9) & 3;
    int lane = (r >> 3) & 63;
    int j = r & 7;
    int m = lane & 15, q = lane >> 4;
    int k = ktb * 32 + q * 8 + j;
    int n = t * 16 + m;
    const float* W = (mat == 0) ? fc1_W : (mat == 1) ? fc2_W : gcn_W + (size_t)(mat - 2) * 16384;
    Wb[idx] = (_Float16)W[(size_t)k * 128 + n];
  } else if (idx < 5 * 16384 + 2048) {
    int r = idx - 5 * 16384;
    int ktb = r >> 9;
    int lane = (r >> 3) & 63;
    int j = r & 7;
    int m = lane & 15, q = lane >> 4;
    int k = ktb * 32 + q * 8 + j;
    Wb[idx] = (_Float16)assign_W[(size_t)k * 16 + m];
  }
}

// ---------------------------------------------------------------- GEMM v3
// Per wave: hoist 8 B-frags (loop-invariant), then NITER 16-row tiles with
// A-frags for tile i+1 prefetched while tile i's MFMAs run. Source order puts
// next-tile loads before current-tile MFMA so the compiler can emit partial
// vmcnt waits (it auto-inserts fine-grained counts).
template <bool SIG, bool HIN, bool HOUT, int NITER>
__global__ __launch_bounds__(256) void gemm128v3_k(const void* __restrict__ Av,
                                                   const _Float16* __restrict__ Wb,
                                                   const float* __restrict__ bias,
                                                   const float* __restrict__ scale,
                                                   void* __restrict__ outv, int N) {
  const int tid = threadIdx.x;
  const int w = tid >> 6, lane = tid & 63;
  const int m = lane & 15, q = lane >> 4;
  const int t0 = w * 2;
  // B fragments: loaded once per wave (32 VGPRs)
  half8 bf[2][4];
#pragma unroll
  for (int t = 0; t < 2; ++t)
#pragma unroll
    for (int ktb = 0; ktb < 4; ++ktb)
      bf[t][ktb] = *(const half8*)(Wb + ((size_t)((t0 + t) * 4 + ktb) * 64 + lane) * 8);

  const int tile0 = blockIdx.x * NITER;
  half8 a_cur[4], a_nxt[4];

#define LOAD_A(TL, DST)                                                                  \
  {                                                                                      \
    int rowA_ = (TL)*16 + m;                                                             \
    if (rowA_ < N) {                                                                     \
      if (HIN) {                                                                         \
        const _Float16* Ap_ = (const _Float16*)Av + (size_t)rowA_ * 128 + q * 8;         \
        _Pragma("unroll") for (int kb_ = 0; kb_ < 4; ++kb_) DST[kb_] =                   \
            *(const half8*)(Ap_ + kb_ * 32);                                             \
      } else {                                                                           \
        const float* Ap_ = (const float*)Av + (size_t)rowA_ * 128 + q * 8;               \
        _Pragma("unroll") for (int kb_ = 0; kb_ < 4; ++kb_) {                            \
          float4 f0_ = *(const float4*)(Ap_ + kb_ * 32);                                 \
          float4 f1_ = *(const float4*)(Ap_ + kb_ * 32 + 4);                             \
          DST[kb_][0] = (_Float16)f0_.x; DST[kb_][1] = (_Float16)f0_.y;                  \
          DST[kb_][2] = (_Float16)f0_.z; DST[kb_][3] = (_Float16)f0_.w;                  \
          DST[kb_][4] = (_Float16)f1_.x; DST[kb_][5] = (_Float16)f1_.y;                  \
          DST[kb_][6] = (_Float16)f1_.z; DST[kb_][7] = (_Float16)f1_.w;                  \
        }                                                                                \
      }                                                                                  \
    } else {                                                                             \
      _Pragma("unroll") for (int kb_ = 0; kb_ < 4; ++kb_) DST[kb_] =                     \
          (half8){0, 0, 0, 0, 0, 0, 0, 0};                                               \
    }                                                                                    \
  }

  LOAD_A(tile0, a_cur);
#pragma unroll
  for (int i = 0; i < NITER; ++i) {
    if (i + 1 < NITER) LOAD_A(tile0 + i + 1, a_nxt);
    floatx4 acc0 = (floatx4){0.f, 0.f, 0.f, 0.f};
    floatx4 acc1 = (floatx4){0.f, 0.f, 0.f, 0.f};
#pragma unroll
    for (int ktb = 0; ktb < 4; ++ktb) {
      acc0 = __builtin_amdgcn_mfma_f32_16x16x32_f16(a_cur[ktb], bf[0][ktb], acc0, 0, 0, 0);
      acc1 = __builtin_amdgcn_mfma_f32_16x16x32_f16(a_cur[ktb], bf[1][ktb], acc1, 0, 0, 0);
    }
    int r0 = (tile0 + i) * 16;
#pragma unroll
    for (int r = 0; r < 4; ++r) {
      int row = r0 + q * 4 + r;
      if (row >= N) continue;
      float sc = scale ? scale[row] : 1.f;
#pragma unroll
      for (int t = 0; t < 2; ++t) {
        int colg = (t0 + t) * 16 + m;
        float v = (t == 0) ? acc0[r] : acc1[r];
        if (bias) v += bias[colg];
        if (SIG) v = 1.f / (1.f + __expf(-v));
        v *= sc;
        if (HOUT)
          ((_Float16*)outv)[(size_t)row * 128 + colg] = (_Float16)v;
        else
          ((float*)outv)[(size_t)row * 128 + colg] = v;
      }
    }
#pragma unroll
    for (int ktb = 0; ktb < 4; ++ktb) a_cur[ktb] = a_nxt[ktb];
  }
#undef LOAD_A
}

// Assign head: out[N,16] fp32 = A[N,128](f16) @ W[128,16], *scale.
// B hoisted; NITER 16-row tiles per wave with A-prefetch.
template <int NITER>
__global__ __launch_bounds__(256) void gemm16v3_k(const _Float16* __restrict__ Av,
                                                  const _Float16* __restrict__ Wb16,
                                                  const float* __restrict__ scale,
                                                  float* __restrict__ out, int N) {
  const int tid = threadIdx.x;
  const int w = tid >> 6, lane = tid & 63;
  const int m = lane & 15, q = lane >> 4;
  half8 bf[4];
#pragma unroll
  for (int ktb = 0; ktb < 4; ++ktb)
    bf[ktb] = *(const half8*)(Wb16 + ((size_t)ktb * 64 + lane) * 8);
  const int tile0 = (blockIdx.x * 4 + w) * NITER;
  half8 a_cur[4], a_nxt[4];
#define LOAD_A16(TL, DST)                                                              \
  {                                                                                    \
    int rowA_ = (TL)*16 + m;                                                           \
    if (rowA_ < N) {                                                                   \
      const _Float16* Ap_ = Av + (size_t)rowA_ * 128 + q * 8;                          \
      _Pragma("unroll") for (int kb_ = 0; kb_ < 4; ++kb_) DST[kb_] =                   \
          *(const half8*)(Ap_ + kb_ * 32);                                             \
    } else {                                                                           \
      _Pragma("unroll") for (int kb_ = 0; kb_ < 4; ++kb_) DST[kb_] =                   \
          (half8){0, 0, 0, 0, 0, 0, 0, 0};                                             \
    }                                                                                  \
  }
  LOAD_A16(tile0, a_cur);
#pragma unroll
  for (int i = 0; i < NITER; ++i) {
    if (i + 1 < NITER) LOAD_A16(tile0 + i + 1, a_nxt);
    floatx4 acc = (floatx4){0.f, 0.f, 0.f, 0.f};
#pragma unroll
    for (int ktb = 0; ktb < 4; ++ktb)
      acc = __builtin_amdgcn_mfma_f32_16x16x32_f16(a_cur[ktb], bf[ktb], acc, 0, 0, 0);
    int r0 = (tile0 + i) * 16;
#pragma unroll
    for (int r = 0; r < 4; ++r) {
      int row = r0 + q * 4 + r;
      if (row < N) out[(size_t)row * 16 + m] = acc[r] * scale[row];
    }
#pragma unroll
    for (int ktb = 0; ktb < 4; ++ktb) a_cur[ktb] = a_nxt[ktb];
  }
#undef LOAD_A16
}

// ---------------------------------------------------------------- aggregation
// xw (f16, pre-scaled by dinv[row]): out[i] = b + dinv[i]*(xw[i]+sum xw[src]).
// One wave/node; 16 lanes x half8 cover the row. Slot j (lane>>4) handles a
// contiguous quarter of the edge list, gathered 4-wide with packed-f16 adds.
__global__ __launch_bounds__(256) void agg128h_k(const _Float16* __restrict__ xw,
                                                 const int* __restrict__ rowptr,
                                                 const int* __restrict__ col,
                                                 const float* __restrict__ dinv,
                                                 const float* __restrict__ bias,
                                                 _Float16* __restrict__ out, int N) {
  int node = blockIdx.x * 4 + (threadIdx.x >> 6);
  if (node >= N) return;
  int lane = threadIdx.x & 63;
  int fl = lane & 15;
  int j = lane >> 4;
  int beg = rowptr[node];
  int end = rowptr[node + 1];
  int deg = end - beg;
  const _Float16* base = xw + (size_t)fl * 8;
  half8 ah = {0, 0, 0, 0, 0, 0, 0, 0};
  int q = (deg + 3) >> 2;
  int e = beg + j * q;
  int e1 = min(e + q, end);
  for (; e + 3 < e1; e += 4) {
    int s0 = col[e], s1 = col[e + 1], s2 = col[e + 2], s3 = col[e + 3];
    half8 v0 = *(const half8*)(base + (size_t)s0 * 128);
    half8 v1 = *(const half8*)(base + (size_t)s1 * 128);
    half8 v2 = *(const half8*)(base + (size_t)s2 * 128);
    half8 v3 = *(const half8*)(base + (size_t)s3 * 128);
    ah += (v0 + v1) + (v2 + v3);
  }
  if (e + 1 < e1) {
    int s0 = col[e], s1 = col[e + 1];
    half8 v0 = *(const half8*)(base + (size_t)s0 * 128);
    half8 v1 = *(const half8*)(base + (size_t)s1 * 128);
    ah += v0 + v1;
    e += 2;
  }
  if (e < e1) {
    ah += *(const half8*)(base + (size_t)col[e] * 128);
  }
  if (j == 0) {  // self-loop term once
    ah += *(const half8*)(base + (size_t)node * 128);
  }
  float a[8];
#pragma unroll
  for (int f = 0; f < 8; ++f) a[f] = (float)ah[f];
#pragma unroll
  for (int f = 0; f < 8; ++f) {
    a[f] += __shfl_xor(a[f], 16, 64);
    a[f] += __shfl_xor(a[f], 32, 64);
  }
  if (j == 0) {
    float di = dinv[node];
    float4 b0 = *(const float4*)(bias + fl * 8);
    float4 b1 = *(const float4*)(bias + fl * 8 + 4);
    half8 o;
    o[0] = (_Float16)fmaf(a[0], di, b0.x);
    o[1] = (_Float16)fmaf(a[1], di, b0.y);
    o[2] = (_Float16)fmaf(a[2], di, b0.z);
    o[3] = (_Float16)fmaf(a[3], di, b0.w);
    o[4] = (_Float16)fmaf(a[4], di, b1.x);
    o[5] = (_Float16)fmaf(a[5], di, b1.y);
    o[6] = (_Float16)fmaf(a[6], di, b1.z);
    o[7] = (_Float16)fmaf(a[7], di, b1.w);
    *(half8*)(out + (size_t)node * 128 + fl * 8) = o;
  }
}

__global__ __launch_bounds__(256) void agg16_k(const float* __restrict__ xw,
                                               const int* __restrict__ rowptr,
                                               const int* __restrict__ col,
                                               const float* __restrict__ dinv,
                                               const float* __restrict__ bias,
                                               float* __restrict__ out, int N) {
  int node = blockIdx.x * 4 + (threadIdx.x >> 6);
  if (node >= N) return;
  int lane = threadIdx.x & 63;
  int f = lane & 15;
  int j = lane >> 4;
  int beg = rowptr[node];
  int end = rowptr[node + 1];
  int deg = end - beg;
  int q = (deg + 3) >> 2;
  int e = beg + j * q;
  int e1 = min(e + q, end);
  float acc = 0.f;
  for (; e + 3 < e1; e += 4) {
    float v0 = xw[(size_t)col[e] * 16 + f];
    float v1 = xw[(size_t)col[e + 1] * 16 + f];
    float v2 = xw[(size_t)col[e + 2] * 16 + f];
    float v3 = xw[(size_t)col[e + 3] * 16 + f];
    acc += (v0 + v1) + (v2 + v3);
  }
  for (; e < e1; ++e) acc += xw[(size_t)col[e] * 16 + f];
  acc += __shfl_xor(acc, 16, 64);
  acc += __shfl_xor(acc, 32, 64);
  float o = fmaf(acc + xw[(size_t)node * 16 + f], dinv[node], bias[f]);
  if (j == 0) out[(size_t)node * 16 + f] = o;
}

// ---------------------------------------------------------------- launch
extern "C" void kernel_launch(void* const* d_in, const int* in_sizes, int n_in,
                              void* d_out, int out_size, void* d_ws, size_t ws_size,
                              hipStream_t stream) {
  const int* adj = (const int*)d_in[0];
  const float* X = (const float*)d_in[1];
  const float* fc1_W = (const float*)d_in[2];
  const float* fc1_b = (const float*)d_in[3];
  const float* fc2_W = (const float*)d_in[4];
  const float* fc2_b = (const float*)d_in[5];
  const float* gcn_W = (const float*)d_in[6];
  const float* gcn_b = (const float*)d_in[7];
  const float* assign_W = (const float*)d_in[8];
  const float* assign_b = (const float*)d_in[9];
  const int E = in_sizes[0] / 2;
  const int N = in_sizes[1] / 128;
  const int* src = adj;
  const int* dst = adj + E;

  char* ws = (char*)d_ws;
  size_t off = 0;
  auto alloc = [&](size_t bytes) {
    void* p = ws + off;
    off = (off + bytes + 511) & ~(size_t)511;
    return p;
  };
  const int G = 256;
  const int B = (N + 511) >> 9;
  const int L = B * G;
  _Float16* Ph = (_Float16*)alloc((size_t)N * 128 * 2);  // 25.6 MB
  _Float16* Qh = (_Float16*)alloc((size_t)N * 128 * 2);  // 25.6 MB
  _Float16* Wb = (_Float16*)alloc((5 * 16384 + 2048) * 2);
  float* dinv = (float*)alloc((size_t)N * 4);
  int* rowptr = (int*)alloc((size_t)(N + 1) * 4);
  int* col = (int*)alloc((size_t)E * 4);
  uint32_t* tmp = (uint32_t*)alloc((size_t)E * 4);
  int* M = (int*)alloc((size_t)L * 4);
  int* scanned = (int*)alloc((size_t)(L + 1) * 4);
  int* scanscratch = (int*)alloc((size_t)L * 4);
  int* bsum = (int*)alloc(4096);
  int* cnt = (int*)alloc((size_t)N * 4);     // fallback path only
  int* cursor = (int*)alloc((size_t)N * 4);  // fallback path only
  float* S = (float*)Ph;  // assign xw [N,16] fp32 reuses Ph

  wprep_k<<<(5 * 16384 + 2048 + 255) / 256, 256, 0, stream>>>(fc1_W, fc2_W, gcn_W, assign_W, Wb);

  if (N <= (1 << 17)) {
    const int chunk = (E + G - 1) / G;
    const int NBL = (L + SCAN_CHUNK - 1) / SCAN_CHUNK;
    p1a_hist_k<<<G, 256, 0, stream>>>(dst, E, G, B, chunk, M);
    scan_partial_k<<<NBL, 256, 0, stream>>>(M, L, bsum);
    scan_bsum_k<<<1, 64, 0, stream>>>(bsum, NBL);
    scan_apply_k<<<NBL, 256, 0, stream>>>(M, bsum, L, scanned, scanscratch, E);
    p1c_scatter_k<<<G, 256, 0, stream>>>(src, dst, E, G, B, chunk, scanned, tmp);
    p2_build_k<<<B, 256, 0, stream>>>(tmp, scanned, G, N, E, rowptr, col, dinv);
  } else {
    const int NB = (N + SCAN_CHUNK - 1) / SCAN_CHUNK;
    hipMemsetAsync(cnt, 0, (size_t)N * 4, stream);
    count_edges_k<<<2048, 256, 0, stream>>>(dst, E, cnt);
    dinv_k<<<(N + 255) / 256, 256, 0, stream>>>(cnt, dinv, N);
    scan_partial_k<<<NB, 256, 0, stream>>>(cnt, N, bsum);
    scan_bsum_k<<<1, 64, 0, stream>>>(bsum, NB);
    scan_apply_k<<<NB, 256, 0, stream>>>(cnt, bsum, N, rowptr, cursor, E);
    fill_k<<<2048, 256, 0, stream>>>(src, dst, E, cursor, col);
  }

  constexpr int NIT = 4;
  int ntiles = (N + 15) / 16;
  int g3 = (ntiles + NIT - 1) / NIT;                 // gemm128v3 blocks
  int g16v3 = (ntiles + 4 * NIT - 1) / (4 * NIT);    // gemm16v3 blocks
  int ab = (N + 3) / 4;
  gemm128v3_k<true, false, true, NIT><<<g3, 256, 0, stream>>>(X, Wb, fc1_b, nullptr, Ph, N);
  gemm128v3_k<true, true, true, NIT><<<g3, 256, 0, stream>>>(Ph, Wb + 16384, fc2_b, nullptr, Qh, N);
  for (int l = 0; l < 3; ++l) {
    gemm128v3_k<false, true, true, NIT><<<g3, 256, 0, stream>>>(
        Qh, Wb + (size_t)(2 + l) * 16384, nullptr, dinv, Ph, N);
    agg128h_k<<<ab, 256, 0, stream>>>(Ph, rowptr, col, dinv, gcn_b + (size_t)l * 128, Qh, N);
  }
  gemm16v3_k<NIT><<<g16v3, 256, 0, stream>>>(Qh, Wb + 5 * 16384, dinv, S, N);
  agg16_k<<<ab, 256, 0, stream>>>(S, rowptr, col, dinv, assign_b, (float*)d_out, N);
}